// Round 15
// baseline (13170.341 us; speedup 1.0000x reference)
//
#include <hip/hip_runtime.h>

#define S_ELE (256 * 1024)   // one [B=256, H=1024] plane (floats)
#define NBLK 2048
#define GRP  8
#define GSZ  (NBLK / GRP)

typedef float f32x4 __attribute__((ext_vector_type(4)));

struct Ptrs {
    const float *x, *W1, *W1r, *W2, *W2r, *Wout;
    const float *b1, *b2, *bo;
    float *spk1_rec, *mout_rec;
    float *mem1, *mem2, *memo;
    float *w1rt, *w2t, *w2rt, *xw, *S2;
    unsigned *bar, *cnt1, *cnt2;
    unsigned short *idx1, *idx2;
    int t_ch;
};

__device__ __forceinline__ float clip01(float b) { return fminf(fmaxf(b, 0.0f), 1.0f); }
__device__ __forceinline__ float4 ld4(const float* p) { return *reinterpret_cast<const float4*>(p); }
__device__ __forceinline__ void   st4(float* p, float4 v) { *reinterpret_cast<float4*>(p) = v; }

// validated membrane update (round-2 arithmetic), float4 and scalar forms
__device__ __forceinline__ float4 memup(float4 mo, float4 cur, float b, float4* sv)
{
    float4 mn, s;
    mn.x = b * mo.x + cur.x - (mo.x > 1.0f ? 1.0f : 0.0f); s.x = (mn.x - 1.0f) > 0.0f ? 1.0f : 0.0f;
    mn.y = b * mo.y + cur.y - (mo.y > 1.0f ? 1.0f : 0.0f); s.y = (mn.y - 1.0f) > 0.0f ? 1.0f : 0.0f;
    mn.z = b * mo.z + cur.z - (mo.z > 1.0f ? 1.0f : 0.0f); s.z = (mn.z - 1.0f) > 0.0f ? 1.0f : 0.0f;
    mn.w = b * mo.w + cur.w - (mo.w > 1.0f ? 1.0f : 0.0f); s.w = (mn.w - 1.0f) > 0.0f ? 1.0f : 0.0f;
    *sv = s; return mn;
}
__device__ __forceinline__ float memup1(float mo, float cur, float b, float* sv)
{
    float mn = b * mo + cur - (mo > 1.0f ? 1.0f : 0.0f);
    *sv = (mn - 1.0f) > 0.0f ? 1.0f : 0.0f;
    return mn;
}

// two-level grid barrier (round-8/10/11 validated structure)
__device__ __forceinline__ void gbar(unsigned* bar)
{
    __syncthreads();
    if (threadIdx.x == 0) {
        unsigned g = __hip_atomic_load(&bar[0], __ATOMIC_RELAXED, __HIP_MEMORY_SCOPE_AGENT);
        unsigned* gc = &bar[8 + ((int)blockIdx.x & (GRP - 1)) * 32];
        unsigned a = __hip_atomic_fetch_add(gc, 1u, __ATOMIC_ACQ_REL, __HIP_MEMORY_SCOPE_AGENT);
        if (a == GSZ - 1) {
            __hip_atomic_store(gc, 0u, __ATOMIC_RELAXED, __HIP_MEMORY_SCOPE_AGENT);
            unsigned tp = __hip_atomic_fetch_add(&bar[1], 1u, __ATOMIC_ACQ_REL, __HIP_MEMORY_SCOPE_AGENT);
            if (tp == GRP - 1) {
                __hip_atomic_store(&bar[1], 0u, __ATOMIC_RELAXED, __HIP_MEMORY_SCOPE_AGENT);
                __hip_atomic_store(&bar[0], g + 1u, __ATOMIC_RELEASE, __HIP_MEMORY_SCOPE_AGENT);
            }
        }
        while (__hip_atomic_load(&bar[0], __ATOMIC_ACQUIRE, __HIP_MEMORY_SCOPE_AGENT) == g)
            __builtin_amdgcn_s_sleep(2);
    }
    __syncthreads();
}

// 32x32 transpose tile: dst[k][n] = src[n][k]   (LDS 4224 B)
__device__ __forceinline__ void tr32(float* sm, const float* src, float* dst, int tr, int tc)
{
    const int t = (int)threadIdx.x;
    const int r = t >> 3, c4 = (t & 7) << 2;
    __syncthreads();
    float4 v = ld4(src + (size_t)(tr * 32 + r) * 1024 + tc * 32 + c4);
    sm[r * 33 + c4 + 0] = v.x; sm[r * 33 + c4 + 1] = v.y;
    sm[r * 33 + c4 + 2] = v.z; sm[r * 33 + c4 + 3] = v.w;
    __syncthreads();
    const int kk = t >> 3, nn4 = (t & 7) << 2;
    float4 o;
    o.x = sm[(nn4 + 0) * 33 + kk]; o.y = sm[(nn4 + 1) * 33 + kk];
    o.z = sm[(nn4 + 2) * 33 + kk]; o.w = sm[(nn4 + 3) * 33 + kk];
    st4(dst + (size_t)(tc * 32 + kk) * 1024 + tr * 32 + nn4, o);
}

// dense 128x128 tile of x_t @ W1^T, K=512, k-chunk 4 (LDS 4224 B).
// Per-output-element fmaf chain is k-ascending -> bitwise = validated version.
__device__ __forceinline__ void xw_tile(float* sm, const float* xA, const float* W1,
                                        float* out, int tm, int tn)
{
    float* As = sm;            // [4][132]
    float* Bs = sm + 528;      // [4][132]
    const int t = (int)threadIdx.x;
    const int half = t >> 7;           // 0: A rows, 1: B rows
    const int row  = t & 127;
    const int r0 = (t >> 4) << 3;
    const int c0 = (t & 15) << 3;
    const float* Ab = xA + (size_t)(tm * 128) * 51200;
    const float* Bb = W1 + (size_t)(tn * 128) * 512;
    const float* src = half ? (Bb + (size_t)row * 512) : (Ab + (size_t)row * 51200);
    float* dstbase = half ? Bs : As;

    float4 pv = ld4(src);
    float acc[8][8] = {};
    for (int c = 0; c < 128; ++c) {
        __syncthreads();
        dstbase[0 * 132 + row] = pv.x; dstbase[1 * 132 + row] = pv.y;
        dstbase[2 * 132 + row] = pv.z; dstbase[3 * 132 + row] = pv.w;
        __syncthreads();
        if (c + 1 < 128) pv = ld4(src + (c + 1) * 4);
        #pragma unroll
        for (int k = 0; k < 4; ++k) {
            float4 a0 = ld4(&As[k * 132 + r0]);
            float4 a1 = ld4(&As[k * 132 + r0 + 4]);
            float4 b0 = ld4(&Bs[k * 132 + c0]);
            float4 b1 = ld4(&Bs[k * 132 + c0 + 4]);
            float av[8] = {a0.x, a0.y, a0.z, a0.w, a1.x, a1.y, a1.z, a1.w};
            float bv[8] = {b0.x, b0.y, b0.z, b0.w, b1.x, b1.y, b1.z, b1.w};
            #pragma unroll
            for (int i = 0; i < 8; ++i)
                #pragma unroll
                for (int j = 0; j < 8; ++j)
                    acc[i][j] = fmaf(av[i], bv[j], acc[i][j]);
        }
    }
    #pragma unroll
    for (int i = 0; i < 8; ++i) {
        float* rowp = out + (size_t)(tm * 128 + r0 + i) * 1024 + tn * 128 + c0;
        st4(rowp,     make_float4(acc[i][0], acc[i][1], acc[i][2], acc[i][3]));
        st4(rowp + 4, make_float4(acc[i][4], acc[i][5], acc[i][6], acc[i][7]));
    }
}

// 1 k-ascending float4 chain, depth-2 prefetch (validated structure)
__device__ __forceinline__ float4 gather1_4(const unsigned short* lst,
    unsigned j, unsigned e, const float* Wt, int n4)
{
    float4 c = make_float4(0.f, 0.f, 0.f, 0.f);
    float4 pa, pb;
    if (j < e)     pa = ld4(Wt + (size_t)lst[j] * 1024 + n4);
    if (j + 1 < e) pb = ld4(Wt + (size_t)lst[j + 1] * 1024 + n4);
    while (j < e) {
        float4 v = pa;
        pa = pb;
        if (j + 2 < e) pb = ld4(Wt + (size_t)lst[j + 2] * 1024 + n4);
        c.x += v.x; c.y += v.y; c.z += v.z; c.w += v.w;
        ++j;
    }
    return c;
}

// 8 concurrent scalar chains, depth-2 prefetch; per-column scalar chain is
// bitwise identical to the float2/float4 versions' per-component chains.
__device__ __forceinline__ void gather8_1(const unsigned short* lst,
    const unsigned pos[9], const float* Wt, int col, float c[8])
{
    unsigned j[8], e[8];
    float pa[8], pb[8];
    #pragma unroll
    for (int q = 0; q < 8; ++q) {
        j[q] = pos[q]; e[q] = pos[q + 1];
        c[q] = 0.0f;
        if (j[q] < e[q])     pa[q] = Wt[(size_t)lst[j[q]] * 1024 + col];
        if (j[q] + 1 < e[q]) pb[q] = Wt[(size_t)lst[j[q] + 1] * 1024 + col];
    }
    for (;;) {
        bool any = false;
        #pragma unroll
        for (int q = 0; q < 8; ++q) {
            if (j[q] < e[q]) {
                float v = pa[q];
                pa[q] = pb[q];
                if (j[q] + 2 < e[q]) pb[q] = Wt[(size_t)lst[j[q] + 2] * 1024 + col];
                c[q] += v;
                ++j[q];
                any = any || (j[q] < e[q]);
            }
        }
        if (!any) break;
    }
}

// segmented list build, full row (windows 0..7), validated
__device__ __forceinline__ void build_seg_full(const float* s_spk,
    unsigned short* gidx, unsigned* gcnt)
{
    const int l = (int)threadIdx.x;   // < 64
    #pragma unroll
    for (int w = 0; w < 8; ++w) {
        unsigned wtot = 0;
        #pragma unroll
        for (int i = 0; i < 2; ++i) {
            const int grp = w * 2 + i;
            float s = s_spk[grp * 64 + l];
            unsigned long long m = __ballot(s != 0.0f);
            unsigned off = (unsigned)__popcll(m & ((1ull << l) - 1ull));
            if (s != 0.0f) gidx[w * 128 + wtot + off] = (unsigned short)(grp * 64 + l);
            wtot += (unsigned)__popcll(m);
        }
        if (l == 0) gcnt[w] = wtot;
    }
}

// segmented list build, quarter q (local spikes s_q[0..255] = cols 256q..)
// -> windows 2q, 2q+1. Same indices, same ascending order as validated.
__device__ __forceinline__ void build_seg_quarter(const float* s_q, int q,
    unsigned short* gidx, unsigned* gcnt)
{
    const int l = (int)threadIdx.x;   // < 64
    #pragma unroll
    for (int wl = 0; wl < 2; ++wl) {
        const int w = 2 * q + wl;
        unsigned wtot = 0;
        #pragma unroll
        for (int i = 0; i < 2; ++i) {
            const int grp = wl * 2 + i;
            float s = s_q[grp * 64 + l];
            unsigned long long m = __ballot(s != 0.0f);
            unsigned off = (unsigned)__popcll(m & ((1ull << l) - 1ull));
            if (s != 0.0f)
                gidx[w * 128 + wtot + off] = (unsigned short)(q * 256 + grp * 64 + l);
            wtot += (unsigned)__popcll(m);
        }
        if (l == 0) gcnt[w] = wtot;
    }
}

// stage segmented global list into packed LDS list (pos[] prefix layout)
__device__ __forceinline__ void stage_list(unsigned short* sl,
    const unsigned short* gseg, const unsigned* cw, const unsigned pos[9])
{
    const int t = (int)threadIdx.x;
    #pragma unroll
    for (int w = 0; w < 8; ++w)
        for (unsigned i = t; i < cw[w]; i += 256)
            sl[pos[w] + i] = gseg[w * 128 + i];
}

// fused L1 quarter-row: 8 concurrent window-chains over cols [256q,256q+256),
// acc = xw + c0 + ... + c7 (validated order), update, record, list build.
__device__ __forceinline__ void l1_quarter(float* sm, const Ptrs& p, int r, int q, int tau)
{
    const int t = (int)threadIdx.x;
    const int col = q * 256 + t;
    const int pp = 1 - (tau & 1);
    const unsigned* cw = p.cnt1 + ((size_t)pp * 256 + r) * 8;
    unsigned pos[9];
    pos[0] = 0;
    #pragma unroll
    for (int w = 0; w < 8; ++w) pos[w + 1] = pos[w] + cw[w];
    unsigned short* sl16 = (unsigned short*)(sm + 256);
    stage_list(sl16, p.idx1 + ((size_t)pp * 256 + r) * 1024, cw, pos);
    __syncthreads();

    float c[8];
    gather8_1(sl16, pos, p.w1rt, col, c);

    const size_t base = (size_t)r * 1024 + col;
    const int slot = tau % p.t_ch;
    float acc = p.xw[(size_t)slot * S_ELE + base];
    #pragma unroll
    for (int w = 0; w < 8; ++w) acc += c[w];
    const float bb = clip01(*p.b1);
    float sv;
    float mn = memup1(p.mem1[base], acc, bb, &sv);
    p.mem1[base] = mn;
    __builtin_nontemporal_store(sv, &p.spk1_rec[(size_t)tau * S_ELE + base]);
    sm[t] = sv;
    __syncthreads();
    if (t < 64) build_seg_quarter(sm, q, p.idx1 + ((size_t)(tau & 1) * 256 + r) * 1024,
                                  p.cnt1 + ((size_t)(tau & 1) * 256 + r) * 8);
}

// L2 gather: family fam (0=w2lo 1=w2hi 2=w2rlo 3=w2rhi), one row, full width.
// Chain content/order bitwise identical to round-10/11/14 chains.
__device__ __forceinline__ void l2g1(float* sm, const Ptrs& p, int r, int fam, int step)
{
    const int t = (int)threadIdx.x, n4 = t << 2;
    const bool rsel = fam >= 2;
    const bool hi = fam & 1;
    const int par = rsel ? (1 - (step & 1)) : (step & 1);
    const unsigned* cw = ((rsel ? p.cnt2 : p.cnt1) + (size_t)par * 256 * 8) + (size_t)r * 8;
    const unsigned short* gseg = ((rsel ? p.idx2 : p.idx1) + (size_t)par * 256 * 1024)
                                 + (size_t)r * 1024;
    const float* W = rsel ? p.w2rt : p.w2t;

    unsigned pos[9];
    pos[0] = 0;
    #pragma unroll
    for (int w = 0; w < 8; ++w) pos[w + 1] = pos[w] + cw[w];
    unsigned short* sl = (unsigned short*)sm;
    stage_list(sl, gseg, cw, pos);
    __syncthreads();
    const unsigned st = hi ? pos[4] : 0;
    const unsigned en = hi ? pos[8] : pos[4];
    float4 c = gather1_4(sl, st, en, W, n4);
    st4(p.S2 + (size_t)fam * S_ELE + (size_t)r * 1024 + n4, c);
}

// update layer 2 + readout: cur = (p0+p1)+(p2+p3) — bitwise round-10 tree
__device__ __forceinline__ void upd2_row(float* sm, const Ptrs& p, int r, int step)
{
    const int t = (int)threadIdx.x, n4 = t << 2;
    const size_t base = (size_t)r * 1024 + n4;
    float4 p0 = ld4(p.S2 + base);
    float4 p1 = ld4(p.S2 + (size_t)S_ELE + base);
    float4 p2 = ld4(p.S2 + (size_t)2 * S_ELE + base);
    float4 p3 = ld4(p.S2 + (size_t)3 * S_ELE + base);
    float4 cur;
    cur.x = (p0.x + p1.x) + (p2.x + p3.x);
    cur.y = (p0.y + p1.y) + (p2.y + p3.y);
    cur.z = (p0.z + p1.z) + (p2.z + p3.z);
    cur.w = (p0.w + p1.w) + (p2.w + p3.w);
    const float bb = clip01(*p.b2);
    float4 mo = ld4(p.mem2 + base);
    float4 sv; float4 mn = memup(mo, cur, bb, &sv);
    st4(p.mem2 + base, mn);
    sm[n4 + 0] = sv.x; sm[n4 + 1] = sv.y; sm[n4 + 2] = sv.z; sm[n4 + 3] = sv.w;
    __syncthreads();
    if (t < 64) build_seg_full(sm, p.idx2 + ((size_t)(step & 1) * 256 + r) * 1024,
                               p.cnt2 + ((size_t)(step & 1) * 256 + r) * 8);
    const int wave = t >> 6, lane = t & 63;
    const float bo = clip01(*p.bo);
    float v[16];
    #pragma unroll
    for (int i = 0; i < 16; ++i) v[i] = sm[lane + 64 * i];
    float* rec = p.mout_rec + (size_t)step * 2560;
    for (int o = wave; o < 10; o += 4) {
        float sum = 0.0f;
        #pragma unroll
        for (int i = 0; i < 16; ++i)
            sum = fmaf(v[i], p.Wout[o * 1024 + lane + 64 * i], sum);
        #pragma unroll
        for (int off = 32; off > 0; off >>= 1) sum += __shfl_down(sum, off);
        if (lane == 0) {
            const float m = bo * p.memo[r * 10 + o] + sum;
            p.memo[r * 10 + o] = m;
            __builtin_nontemporal_store(m, &rec[r * 10 + o]);
        }
    }
}

// ---- persistent cooperative kernel: 2048 blocks (8/CU, 32 waves/CU) ----
// XCD 0-3: L1 quarter-rows (1 MB w1rt slice resident per XCD);
// XCD 4-7: one L2 family each (2 MB k-half shard resident).
__global__ __launch_bounds__(256, 8) void snn_all(Ptrs p)
{
    __shared__ float sm[1088];          // 4352 B
    const int bid = (int)blockIdx.x;
    const int x = bid & 7, g = bid >> 3;   // g in 0..255

    for (int task = bid; task < 3072; task += NBLK) {
        const float* src = task < 1024 ? p.W1r : (task < 2048 ? p.W2 : p.W2r);
        float* dst = task < 1024 ? p.w1rt : (task < 2048 ? p.w2t : p.w2rt);
        const int id = task & 1023;
        tr32(sm, src, dst, id >> 5, id & 31);
    }
    gbar(p.bar);

    for (int tau = 0; tau <= 100; ++tau) {
        if (tau < 100 && (tau % p.t_ch) == 0) {
            const int ntask = p.t_ch * 16;
            for (int task = bid; task < ntask; task += NBLK) {
                const int tp = task >> 4, tile = task & 15;
                xw_tile(sm, p.x + (size_t)(tau + tp) * 512, p.W1,
                        p.xw + (size_t)tp * S_ELE, tile >> 3, tile & 7);
            }
            gbar(p.bar);
        }
        // phase 1: L1(tau) quarter-rows || L2 family gathers for step tau-1
        if (x < 4) {
            if (tau < 100) l1_quarter(sm, p, g, x, tau);
        } else {
            if (tau >= 1) l2g1(sm, p, g, x - 4, tau - 1);
        }
        gbar(p.bar);
        // phase 2: upd2 + readout for step tau-1
        if (bid < 256 && tau >= 1) upd2_row(sm, p, bid, tau - 1);
        gbar(p.bar);
    }
}

// ---- fallback kernels (kernel boundaries as barriers) ----
__global__ __launch_bounds__(256, 8) void fb_pre(Ptrs p)
{
    __shared__ float sm[1088];
    for (int task = blockIdx.x; task < 3072; task += gridDim.x) {
        const float* src = task < 1024 ? p.W1r : (task < 2048 ? p.W2 : p.W2r);
        float* dst = task < 1024 ? p.w1rt : (task < 2048 ? p.w2t : p.w2rt);
        const int id = task & 1023;
        tr32(sm, src, dst, id >> 5, id & 31);
    }
}

__global__ __launch_bounds__(256, 8) void fb_xw(Ptrs p, int t0)
{
    __shared__ float sm[1088];
    const int task = (int)blockIdx.x;
    const int tp = task >> 4, tile = task & 15;
    xw_tile(sm, p.x + (size_t)(t0 + tp) * 512, p.W1,
            p.xw + (size_t)tp * S_ELE, tile >> 3, tile & 7);
}

__global__ __launch_bounds__(256, 8) void fb_p1(Ptrs p, int tau)
{
    __shared__ float sm[1088];
    const int bid = (int)blockIdx.x;
    const int x = bid & 7, g = bid >> 3;
    if (x < 4) {
        if (tau < 100) l1_quarter(sm, p, g, x, tau);
    } else {
        if (tau >= 1) l2g1(sm, p, g, x - 4, tau - 1);
    }
}

__global__ __launch_bounds__(256, 8) void fb_p2(Ptrs p, int tau)
{
    __shared__ float sm[1088];
    if (tau >= 1) upd2_row(sm, p, (int)blockIdx.x, tau - 1);
}

extern "C" void kernel_launch(void* const* d_in, const int* in_sizes, int n_in,
                              void* d_out, int out_size, void* d_ws, size_t ws_size,
                              hipStream_t stream)
{
    Ptrs p;
    p.x    = (const float*)d_in[0];
    p.W1   = (const float*)d_in[1];
    p.W1r  = (const float*)d_in[2];
    p.W2   = (const float*)d_in[3];
    p.W2r  = (const float*)d_in[4];
    p.Wout = (const float*)d_in[5];
    p.b1   = (const float*)d_in[6];
    p.b2   = (const float*)d_in[7];
    p.bo   = (const float*)d_in[8];

    float* out = (float*)d_out;
    p.spk1_rec = out;
    p.mout_rec = out + (size_t)100 * S_ELE;

    float* w = (float*)d_ws;
    p.mem1 = w;  w += S_ELE;
    p.mem2 = w;  w += S_ELE;
    p.memo = w;  w += 2560;
    p.bar  = (unsigned*)w;  w += 512;
    p.cnt1 = (unsigned*)w;  w += 4096;
    p.cnt2 = (unsigned*)w;  w += 4096;
    p.idx1 = (unsigned short*)w;  w += 262144;
    p.idx2 = (unsigned short*)w;  w += 262144;
    p.w1rt = w;  w += 1048576;
    p.w2t  = w;  w += 1048576;
    p.w2rt = w;  w += 1048576;
    p.S2   = w;  w += 4 * S_ELE;
    p.xw   = w;

    const size_t used = (size_t)(w - (float*)d_ws) * sizeof(float);
    int t_ch = 1;
    const int cands[] = {100, 50, 25, 20, 10, 5, 4, 2, 1};
    for (int c : cands)
        if (used + (size_t)c * S_ELE * sizeof(float) <= ws_size) { t_ch = c; break; }
    p.t_ch = t_ch;

    // zero mem1, mem2, memo, bar, cnt1, cnt2 (contiguous)
    (void)hipMemsetAsync(p.mem1, 0,
                   ((size_t)2 * S_ELE + 2560 + 512 + 8192) * sizeof(float), stream);

    int maxb = 0;
    hipError_t qerr = hipOccupancyMaxActiveBlocksPerMultiprocessor(
        &maxb, (const void*)snn_all, 256, 0);
    bool coop = (qerr == hipSuccess && maxb >= 8);

    if (coop) {
        void* args[] = { (void*)&p };
        if (hipLaunchCooperativeKernel((const void*)snn_all, dim3(NBLK), dim3(256),
                                       args, 0, stream) != hipSuccess)
            coop = false;
    }

    if (!coop) {
        hipLaunchKernelGGL(fb_pre, dim3(NBLK), dim3(256), 0, stream, p);
        for (int tau = 0; tau <= 100; ++tau) {
            if (tau < 100 && (tau % t_ch) == 0)
                hipLaunchKernelGGL(fb_xw, dim3(t_ch * 16), dim3(256), 0, stream, p, tau);
            hipLaunchKernelGGL(fb_p1, dim3(NBLK), dim3(256), 0, stream, p, tau);
            hipLaunchKernelGGL(fb_p2, dim3(256), dim3(256), 0, stream, p, tau);
        }
    }
}

// Round 16
// 3983.374 us; speedup vs baseline: 3.3063x; 3.3063x over previous
//
#include <hip/hip_runtime.h>

#define S_ELE (256 * 1024)   // one [B=256, H=1024] plane (floats)
#define NBLK 1024
#define GRP  8
#define GSZ  (NBLK / GRP)

typedef float f32x4 __attribute__((ext_vector_type(4)));
typedef float f32x2 __attribute__((ext_vector_type(2)));

struct Ptrs {
    const float *x, *W1, *W1r, *W2, *W2r, *Wout;
    const float *b1, *b2, *bo;
    float *spk1_rec, *mout_rec;
    float *mem1, *mem2, *memo;
    float *w1rt, *w2t, *w2rt, *xw, *S2;
    unsigned *bar, *cnt1, *cnt2;
    unsigned short *idx1, *idx2;
    int t_ch;
};

__device__ __forceinline__ float clip01(float b) { return fminf(fmaxf(b, 0.0f), 1.0f); }
__device__ __forceinline__ float4 ld4(const float* p) { return *reinterpret_cast<const float4*>(p); }
__device__ __forceinline__ void   st4(float* p, float4 v) { *reinterpret_cast<float4*>(p) = v; }
__device__ __forceinline__ float2 ld2(const float* p) { return *reinterpret_cast<const float2*>(p); }
__device__ __forceinline__ void   st2(float* p, float2 v) { *reinterpret_cast<float2*>(p) = v; }
__device__ __forceinline__ void   st2nt(float* p, float2 v)
{
    f32x2 n = { v.x, v.y };
    __builtin_nontemporal_store(n, reinterpret_cast<f32x2*>(p));
}

// validated membrane update (round-2 arithmetic), float4 and float2 forms
__device__ __forceinline__ float4 memup(float4 mo, float4 cur, float b, float4* sv)
{
    float4 mn, s;
    mn.x = b * mo.x + cur.x - (mo.x > 1.0f ? 1.0f : 0.0f); s.x = (mn.x - 1.0f) > 0.0f ? 1.0f : 0.0f;
    mn.y = b * mo.y + cur.y - (mo.y > 1.0f ? 1.0f : 0.0f); s.y = (mn.y - 1.0f) > 0.0f ? 1.0f : 0.0f;
    mn.z = b * mo.z + cur.z - (mo.z > 1.0f ? 1.0f : 0.0f); s.z = (mn.z - 1.0f) > 0.0f ? 1.0f : 0.0f;
    mn.w = b * mo.w + cur.w - (mo.w > 1.0f ? 1.0f : 0.0f); s.w = (mn.w - 1.0f) > 0.0f ? 1.0f : 0.0f;
    *sv = s; return mn;
}
__device__ __forceinline__ float2 memup2(float2 mo, float2 cur, float b, float2* sv)
{
    float2 mn, s;
    mn.x = b * mo.x + cur.x - (mo.x > 1.0f ? 1.0f : 0.0f); s.x = (mn.x - 1.0f) > 0.0f ? 1.0f : 0.0f;
    mn.y = b * mo.y + cur.y - (mo.y > 1.0f ? 1.0f : 0.0f); s.y = (mn.y - 1.0f) > 0.0f ? 1.0f : 0.0f;
    *sv = s; return mn;
}

// two-level grid barrier (round-8/10/11 validated structure)
__device__ __forceinline__ void gbar(unsigned* bar)
{
    __syncthreads();
    if (threadIdx.x == 0) {
        unsigned g = __hip_atomic_load(&bar[0], __ATOMIC_RELAXED, __HIP_MEMORY_SCOPE_AGENT);
        unsigned* gc = &bar[8 + ((int)blockIdx.x & (GRP - 1)) * 32];
        unsigned a = __hip_atomic_fetch_add(gc, 1u, __ATOMIC_ACQ_REL, __HIP_MEMORY_SCOPE_AGENT);
        if (a == GSZ - 1) {
            __hip_atomic_store(gc, 0u, __ATOMIC_RELAXED, __HIP_MEMORY_SCOPE_AGENT);
            unsigned tp = __hip_atomic_fetch_add(&bar[1], 1u, __ATOMIC_ACQ_REL, __HIP_MEMORY_SCOPE_AGENT);
            if (tp == GRP - 1) {
                __hip_atomic_store(&bar[1], 0u, __ATOMIC_RELAXED, __HIP_MEMORY_SCOPE_AGENT);
                __hip_atomic_store(&bar[0], g + 1u, __ATOMIC_RELEASE, __HIP_MEMORY_SCOPE_AGENT);
            }
        }
        while (__hip_atomic_load(&bar[0], __ATOMIC_ACQUIRE, __HIP_MEMORY_SCOPE_AGENT) == g)
            __builtin_amdgcn_s_sleep(2);
    }
    __syncthreads();
}

// 32x32 transpose tile: dst[k][n] = src[n][k]
__device__ __forceinline__ void tr32(float* sm, const float* src, float* dst, int tr, int tc)
{
    const int t = (int)threadIdx.x;
    const int r = t >> 3, c4 = (t & 7) << 2;
    __syncthreads();
    float4 v = ld4(src + (size_t)(tr * 32 + r) * 1024 + tc * 32 + c4);
    sm[r * 33 + c4 + 0] = v.x; sm[r * 33 + c4 + 1] = v.y;
    sm[r * 33 + c4 + 2] = v.z; sm[r * 33 + c4 + 3] = v.w;
    __syncthreads();
    const int kk = t >> 3, nn4 = (t & 7) << 2;
    float4 o;
    o.x = sm[(nn4 + 0) * 33 + kk]; o.y = sm[(nn4 + 1) * 33 + kk];
    o.z = sm[(nn4 + 2) * 33 + kk]; o.w = sm[(nn4 + 3) * 33 + kk];
    st4(dst + (size_t)(tc * 32 + kk) * 1024 + tr * 32 + nn4, o);
}

// dense 128x128 tile of x_t @ W1^T, K=512, k-chunk 8, k-ascending chain (validated)
__device__ __forceinline__ void xw_tile(float* sm, const float* xA, const float* W1,
                                        float* out, int tm, int tn)
{
    float* As = sm;            // [8][132]
    float* Bs = sm + 1056;     // [8][132]
    const int t = (int)threadIdx.x;
    const int ar = t >> 1;
    const int ak = (t & 1) << 2;
    const int r0 = (t >> 4) << 3;
    const int c0 = (t & 15) << 3;
    const float* Ab = xA + (size_t)(tm * 128) * 51200;
    const float* Bb = W1 + (size_t)(tn * 128) * 512;
    float4 pa = ld4(Ab + (size_t)ar * 51200 + ak);
    float4 pb = ld4(Bb + (size_t)ar * 512 + ak);
    float acc[8][8] = {};
    for (int c = 0; c < 64; ++c) {
        __syncthreads();
        As[(ak + 0) * 132 + ar] = pa.x; As[(ak + 1) * 132 + ar] = pa.y;
        As[(ak + 2) * 132 + ar] = pa.z; As[(ak + 3) * 132 + ar] = pa.w;
        Bs[(ak + 0) * 132 + ar] = pb.x; Bs[(ak + 1) * 132 + ar] = pb.y;
        Bs[(ak + 2) * 132 + ar] = pb.z; Bs[(ak + 3) * 132 + ar] = pb.w;
        __syncthreads();
        if (c + 1 < 64) {
            const int ko = (c + 1) * 8;
            pa = ld4(Ab + (size_t)ar * 51200 + ko + ak);
            pb = ld4(Bb + (size_t)ar * 512 + ko + ak);
        }
        #pragma unroll
        for (int k = 0; k < 8; ++k) {
            float4 a0 = ld4(&As[k * 132 + r0]);
            float4 a1 = ld4(&As[k * 132 + r0 + 4]);
            float4 b0 = ld4(&Bs[k * 132 + c0]);
            float4 b1 = ld4(&Bs[k * 132 + c0 + 4]);
            float av[8] = {a0.x, a0.y, a0.z, a0.w, a1.x, a1.y, a1.z, a1.w};
            float bv[8] = {b0.x, b0.y, b0.z, b0.w, b1.x, b1.y, b1.z, b1.w};
            #pragma unroll
            for (int i = 0; i < 8; ++i)
                #pragma unroll
                for (int j = 0; j < 8; ++j)
                    acc[i][j] = fmaf(av[i], bv[j], acc[i][j]);
        }
    }
    #pragma unroll
    for (int i = 0; i < 8; ++i) {
        float* row = out + (size_t)(tm * 128 + r0 + i) * 1024 + tn * 128 + c0;
        st4(row,     make_float4(acc[i][0], acc[i][1], acc[i][2], acc[i][3]));
        st4(row + 4, make_float4(acc[i][4], acc[i][5], acc[i][6], acc[i][7]));
    }
}

// NC concurrent k-ascending float4 chains, depth-2 prefetch (validated r6/8/10/11)
template <int NC>
__device__ __forceinline__ void gatherN(const unsigned short* const lp[],
    const unsigned st[], const unsigned en[], const float* Wt, int n4, float4 c[])
{
    unsigned j[NC], e[NC];
    float4 pa[NC], pb[NC];
    #pragma unroll
    for (int q = 0; q < NC; ++q) {
        j[q] = st[q]; e[q] = en[q];
        c[q] = make_float4(0.f, 0.f, 0.f, 0.f);
        if (j[q] < e[q])     pa[q] = ld4(Wt + (size_t)lp[q][j[q]] * 1024 + n4);
        if (j[q] + 1 < e[q]) pb[q] = ld4(Wt + (size_t)lp[q][j[q] + 1] * 1024 + n4);
    }
    for (;;) {
        bool any = false;
        #pragma unroll
        for (int q = 0; q < NC; ++q) {
            if (j[q] < e[q]) {
                float4 v = pa[q];
                pa[q] = pb[q];
                if (j[q] + 2 < e[q]) pb[q] = ld4(Wt + (size_t)lp[q][j[q] + 2] * 1024 + n4);
                c[q].x += v.x; c[q].y += v.y; c[q].z += v.z; c[q].w += v.w;
                ++j[q];
                any = any || (j[q] < e[q]);
            }
        }
        if (!any) break;
    }
}

// 8 concurrent float2 chains (half-width L1 gather), depth-2 (validated r11)
__device__ __forceinline__ void gather8_2(const unsigned short* lst,
    const unsigned pos[9], const float* Wt, int col, float2 c[8])
{
    unsigned j[8], e[8];
    float2 pa[8], pb[8];
    #pragma unroll
    for (int q = 0; q < 8; ++q) {
        j[q] = pos[q]; e[q] = pos[q + 1];
        c[q] = make_float2(0.f, 0.f);
        if (j[q] < e[q])     pa[q] = ld2(Wt + (size_t)lst[j[q]] * 1024 + col);
        if (j[q] + 1 < e[q]) pb[q] = ld2(Wt + (size_t)lst[j[q] + 1] * 1024 + col);
    }
    for (;;) {
        bool any = false;
        #pragma unroll
        for (int q = 0; q < 8; ++q) {
            if (j[q] < e[q]) {
                float2 v = pa[q];
                pa[q] = pb[q];
                if (j[q] + 2 < e[q]) pb[q] = ld2(Wt + (size_t)lst[j[q] + 2] * 1024 + col);
                c[q].x += v.x; c[q].y += v.y;
                ++j[q];
                any = any || (j[q] < e[q]);
            }
        }
        if (!any) break;
    }
}

// segmented list build, full row (16 groups -> windows 0..7), validated
__device__ __forceinline__ void build_seg_full(const float* s_spk,
    unsigned short* gidx, unsigned* gcnt)
{
    const int l = (int)threadIdx.x;   // < 64
    #pragma unroll
    for (int w = 0; w < 8; ++w) {
        unsigned wtot = 0;
        #pragma unroll
        for (int i = 0; i < 2; ++i) {
            const int grp = w * 2 + i;
            float s = s_spk[grp * 64 + l];
            unsigned long long m = __ballot(s != 0.0f);
            unsigned off = (unsigned)__popcll(m & ((1ull << l) - 1ull));
            if (s != 0.0f) gidx[w * 128 + wtot + off] = (unsigned short)(grp * 64 + l);
            wtot += (unsigned)__popcll(m);
        }
        if (l == 0) gcnt[w] = wtot;
    }
}

// segmented list build, half row h (local spikes s_half[0..511] = cols 512h..)
__device__ __forceinline__ void build_seg_half(const float* s_half, int h,
    unsigned short* gidx, unsigned* gcnt)
{
    const int l = (int)threadIdx.x;   // < 64
    #pragma unroll
    for (int wl = 0; wl < 4; ++wl) {
        const int w = 4 * h + wl;
        unsigned wtot = 0;
        #pragma unroll
        for (int i = 0; i < 2; ++i) {
            const int grp = wl * 2 + i;
            float s = s_half[grp * 64 + l];
            unsigned long long m = __ballot(s != 0.0f);
            unsigned off = (unsigned)__popcll(m & ((1ull << l) - 1ull));
            if (s != 0.0f)
                gidx[w * 128 + wtot + off] = (unsigned short)(h * 512 + grp * 64 + l);
            wtot += (unsigned)__popcll(m);
        }
        if (l == 0) gcnt[w] = wtot;
    }
}

// stage segmented global list into packed LDS list (pos[] prefix layout)
__device__ __forceinline__ void stage_list(unsigned short* sl,
    const unsigned short* gseg, const unsigned* cw, const unsigned pos[9])
{
    const int t = (int)threadIdx.x;
    #pragma unroll
    for (int w = 0; w < 8; ++w)
        for (unsigned i = t; i < cw[w]; i += 256)
            sl[pos[w] + i] = gseg[w * 128 + i];
}

// fused L1 half-row: 8 concurrent window-chains over cols [512h,512h+512),
// acc = xw + c0 + ... + c7 (validated order), update, record, list build.
__device__ __forceinline__ void l1_half(float* sm, const Ptrs& p, int r, int h, int tau)
{
    const int t = (int)threadIdx.x;
    const int lc = t * 2;               // local col 0..510
    const int col = h * 512 + lc;
    const int pp = 1 - (tau & 1);
    const unsigned* cw = p.cnt1 + ((size_t)pp * 256 + r) * 8;
    unsigned pos[9];
    pos[0] = 0;
    #pragma unroll
    for (int w = 0; w < 8; ++w) pos[w + 1] = pos[w] + cw[w];
    unsigned short* sl16 = (unsigned short*)(sm + 512);
    stage_list(sl16, p.idx1 + ((size_t)pp * 256 + r) * 1024, cw, pos);
    __syncthreads();

    float2 c[8];
    gather8_2(sl16, pos, p.w1rt, col, c);

    const size_t base = (size_t)r * 1024 + col;
    const int slot = tau % p.t_ch;
    float2 acc = ld2(p.xw + (size_t)slot * S_ELE + base);
    #pragma unroll
    for (int w = 0; w < 8; ++w) { acc.x += c[w].x; acc.y += c[w].y; }
    const float bb = clip01(*p.b1);
    float2 mo = ld2(p.mem1 + base);
    float2 sv; float2 mn = memup2(mo, acc, bb, &sv);
    st2(p.mem1 + base, mn);
    st2nt(p.spk1_rec + (size_t)tau * S_ELE + base, sv);
    sm[lc] = sv.x; sm[lc + 1] = sv.y;
    __syncthreads();
    if (t < 64) build_seg_half(sm, h, p.idx1 + ((size_t)(tau & 1) * 256 + r) * 1024,
                               p.cnt1 + ((size_t)(tau & 1) * 256 + r) * 8);
}

// L2 gather: family fam (0=w2lo 1=w2hi 2=w2rlo 3=w2rhi), rows 2g,2g+1,
// full width. Chain content/order bitwise identical to round-10/11 chains.
__device__ __forceinline__ void l2g2(float* sm, const Ptrs& p, int g, int fam, int step)
{
    const int t = (int)threadIdx.x, n4 = t << 2;
    const bool rsel = fam >= 2;
    const bool hi = fam & 1;
    const int par = rsel ? (1 - (step & 1)) : (step & 1);
    const unsigned* cbase = (rsel ? p.cnt2 : p.cnt1) + (size_t)par * 256 * 8;
    const unsigned short* ibase = (rsel ? p.idx2 : p.idx1) + (size_t)par * 256 * 1024;
    const float* W = rsel ? p.w2rt : p.w2t;

    const unsigned short* lp[2];
    unsigned st[2], en[2];
    #pragma unroll
    for (int q = 0; q < 2; ++q) {
        const int r = 2 * g + q;
        const unsigned* cw = cbase + (size_t)r * 8;
        unsigned pos[9];
        pos[0] = 0;
        #pragma unroll
        for (int w = 0; w < 8; ++w) pos[w + 1] = pos[w] + cw[w];
        unsigned short* sl = (unsigned short*)sm + 1024 * q;
        stage_list(sl, ibase + (size_t)r * 1024, cw, pos);
        lp[q] = sl;
        st[q] = hi ? pos[4] : 0;
        en[q] = hi ? pos[8] : pos[4];
    }
    __syncthreads();
    float4 c[2];
    gatherN<2>(lp, st, en, W, n4, c);
    #pragma unroll
    for (int q = 0; q < 2; ++q)
        st4(p.S2 + (size_t)fam * S_ELE + (size_t)(2 * g + q) * 1024 + n4, c[q]);
}

// update layer 2 + readout: cur = (p0+p1)+(p2+p3) — bitwise round-10 tree
__device__ __forceinline__ void upd2_row(float* sm, const Ptrs& p, int r, int step)
{
    const int t = (int)threadIdx.x, n4 = t << 2;
    const size_t base = (size_t)r * 1024 + n4;
    float4 p0 = ld4(p.S2 + base);
    float4 p1 = ld4(p.S2 + (size_t)S_ELE + base);
    float4 p2 = ld4(p.S2 + (size_t)2 * S_ELE + base);
    float4 p3 = ld4(p.S2 + (size_t)3 * S_ELE + base);
    float4 cur;
    cur.x = (p0.x + p1.x) + (p2.x + p3.x);
    cur.y = (p0.y + p1.y) + (p2.y + p3.y);
    cur.z = (p0.z + p1.z) + (p2.z + p3.z);
    cur.w = (p0.w + p1.w) + (p2.w + p3.w);
    const float bb = clip01(*p.b2);
    float4 mo = ld4(p.mem2 + base);
    float4 sv; float4 mn = memup(mo, cur, bb, &sv);
    st4(p.mem2 + base, mn);
    sm[n4 + 0] = sv.x; sm[n4 + 1] = sv.y; sm[n4 + 2] = sv.z; sm[n4 + 3] = sv.w;
    __syncthreads();
    if (t < 64) build_seg_full(sm, p.idx2 + ((size_t)(step & 1) * 256 + r) * 1024,
                               p.cnt2 + ((size_t)(step & 1) * 256 + r) * 8);
    const int wave = t >> 6, lane = t & 63;
    const float bo = clip01(*p.bo);
    float v[16];
    #pragma unroll
    for (int i = 0; i < 16; ++i) v[i] = sm[lane + 64 * i];
    float* rec = p.mout_rec + (size_t)step * 2560;
    for (int o = wave; o < 10; o += 4) {
        float sum = 0.0f;
        #pragma unroll
        for (int i = 0; i < 16; ++i)
            sum = fmaf(v[i], p.Wout[o * 1024 + lane + 64 * i], sum);
        #pragma unroll
        for (int off = 32; off > 0; off >>= 1) sum += __shfl_down(sum, off);
        if (lane == 0) {
            const float m = bo * p.memo[r * 10 + o] + sum;
            p.memo[r * 10 + o] = m;
            __builtin_nontemporal_store(m, &rec[r * 10 + o]);
        }
    }
}

// ---- persistent cooperative kernel: 1024 blocks (4/CU, 16 waves/CU) ----
// L1 task->XCD remap: XCD = 2h + (r>=128), so each L1 XCD touches only a
// 2 MB column-half slice of w1rt (fits L2 with state).
// XCD 4-7: one L2 family each (2 MB k-half shard resident).
__global__ __launch_bounds__(256, 4) void snn_all(Ptrs p)
{
    __shared__ float sm[2176];          // 8704 B
    const int bid = (int)blockIdx.x;
    const int x = bid & 7, g = bid >> 3;   // g in 0..127

    for (int task = bid; task < 3072; task += NBLK) {
        const float* src = task < 1024 ? p.W1r : (task < 2048 ? p.W2 : p.W2r);
        float* dst = task < 1024 ? p.w1rt : (task < 2048 ? p.w2t : p.w2rt);
        const int id = task & 1023;
        tr32(sm, src, dst, id >> 5, id & 31);
    }
    gbar(p.bar);

    for (int tau = 0; tau <= 100; ++tau) {
        if (tau < 100 && (tau % p.t_ch) == 0) {
            const int ntask = p.t_ch * 16;
            for (int task = bid; task < ntask; task += NBLK) {
                const int tp = task >> 4, tile = task & 15;
                xw_tile(sm, p.x + (size_t)(tau + tp) * 512, p.W1,
                        p.xw + (size_t)tp * S_ELE, tile >> 3, tile & 7);
            }
            gbar(p.bar);
        }
        // phase 1: L1(tau) half-rows || L2 family gathers for step tau-1
        if (x < 4) {
            if (tau < 100) {
                const int h = x >> 1;               // weight column-half
                const int r = (x & 1) * 128 + g;    // row
                l1_half(sm, p, r, h, tau);
            }
        } else {
            if (tau >= 1) l2g2(sm, p, g, x - 4, tau - 1);
        }
        gbar(p.bar);
        // phase 2: upd2 + readout for step tau-1
        if (bid < 256 && tau >= 1) upd2_row(sm, p, bid, tau - 1);
        gbar(p.bar);
    }
}

// ---- fallback kernels (kernel boundaries as barriers) ----
__global__ __launch_bounds__(256, 4) void fb_pre(Ptrs p)
{
    __shared__ float sm[2176];
    for (int task = blockIdx.x; task < 3072; task += gridDim.x) {
        const float* src = task < 1024 ? p.W1r : (task < 2048 ? p.W2 : p.W2r);
        float* dst = task < 1024 ? p.w1rt : (task < 2048 ? p.w2t : p.w2rt);
        const int id = task & 1023;
        tr32(sm, src, dst, id >> 5, id & 31);
    }
}

__global__ __launch_bounds__(256, 4) void fb_xw(Ptrs p, int t0)
{
    __shared__ float sm[2176];
    const int task = (int)blockIdx.x;
    const int tp = task >> 4, tile = task & 15;
    xw_tile(sm, p.x + (size_t)(t0 + tp) * 512, p.W1,
            p.xw + (size_t)tp * S_ELE, tile >> 3, tile & 7);
}

__global__ __launch_bounds__(256, 4) void fb_p1(Ptrs p, int tau)
{
    __shared__ float sm[2176];
    const int bid = (int)blockIdx.x;
    const int x = bid & 7, g = bid >> 3;
    if (x < 4) {
        if (tau < 100) {
            const int h = x >> 1;
            const int r = (x & 1) * 128 + g;
            l1_half(sm, p, r, h, tau);
        }
    } else {
        if (tau >= 1) l2g2(sm, p, g, x - 4, tau - 1);
    }
}

__global__ __launch_bounds__(256, 4) void fb_p2(Ptrs p, int tau)
{
    __shared__ float sm[2176];
    if (tau >= 1) upd2_row(sm, p, (int)blockIdx.x, tau - 1);
}

extern "C" void kernel_launch(void* const* d_in, const int* in_sizes, int n_in,
                              void* d_out, int out_size, void* d_ws, size_t ws_size,
                              hipStream_t stream)
{
    Ptrs p;
    p.x    = (const float*)d_in[0];
    p.W1   = (const float*)d_in[1];
    p.W1r  = (const float*)d_in[2];
    p.W2   = (const float*)d_in[3];
    p.W2r  = (const float*)d_in[4];
    p.Wout = (const float*)d_in[5];
    p.b1   = (const float*)d_in[6];
    p.b2   = (const float*)d_in[7];
    p.bo   = (const float*)d_in[8];

    float* out = (float*)d_out;
    p.spk1_rec = out;
    p.mout_rec = out + (size_t)100 * S_ELE;

    float* w = (float*)d_ws;
    p.mem1 = w;  w += S_ELE;
    p.mem2 = w;  w += S_ELE;
    p.memo = w;  w += 2560;
    p.bar  = (unsigned*)w;  w += 512;
    p.cnt1 = (unsigned*)w;  w += 4096;
    p.cnt2 = (unsigned*)w;  w += 4096;
    p.idx1 = (unsigned short*)w;  w += 262144;
    p.idx2 = (unsigned short*)w;  w += 262144;
    p.w1rt = w;  w += 1048576;
    p.w2t  = w;  w += 1048576;
    p.w2rt = w;  w += 1048576;
    p.S2   = w;  w += 4 * S_ELE;
    p.xw   = w;

    const size_t used = (size_t)(w - (float*)d_ws) * sizeof(float);
    int t_ch = 1;
    const int cands[] = {100, 50, 25, 20, 10, 5, 4, 2, 1};
    for (int c : cands)
        if (used + (size_t)c * S_ELE * sizeof(float) <= ws_size) { t_ch = c; break; }
    p.t_ch = t_ch;

    // zero mem1, mem2, memo, bar, cnt1, cnt2 (contiguous)
    (void)hipMemsetAsync(p.mem1, 0,
                   ((size_t)2 * S_ELE + 2560 + 512 + 8192) * sizeof(float), stream);

    int maxb = 0;
    hipError_t qerr = hipOccupancyMaxActiveBlocksPerMultiprocessor(
        &maxb, (const void*)snn_all, 256, 0);
    bool coop = (qerr == hipSuccess && maxb >= 4);

    if (coop) {
        void* args[] = { (void*)&p };
        if (hipLaunchCooperativeKernel((const void*)snn_all, dim3(NBLK), dim3(256),
                                       args, 0, stream) != hipSuccess)
            coop = false;
    }

    if (!coop) {
        hipLaunchKernelGGL(fb_pre, dim3(NBLK), dim3(256), 0, stream, p);
        for (int tau = 0; tau <= 100; ++tau) {
            if (tau < 100 && (tau % t_ch) == 0)
                hipLaunchKernelGGL(fb_xw, dim3(t_ch * 16), dim3(256), 0, stream, p, tau);
            hipLaunchKernelGGL(fb_p1, dim3(NBLK), dim3(256), 0, stream, p, tau);
            hipLaunchKernelGGL(fb_p2, dim3(256), dim3(256), 0, stream, p, tau);
        }
    }
}